// Round 13
// baseline (143.176 us; speedup 1.0000x reference)
//
#include <hip/hip_runtime.h>

// BitPredictor: scalar LSTM (hidden=1) iterated FEATURES times; output is one
// 512-float row broadcast across the 65536-row batch (batch dim degenerate).
//
// R2:  380us = single-lane serial recurrence -> fixed-point early exit +
//      exp2/rcp gates. Kernel ~40us after.
// R7/R9: opposite store layouts both ~3.2 TB/s vs fill 6.6 -> addressing out.
// R11: fill-like long-lived waves (512 blocks, 64 stores/thread): 40->35us.
//      Wave lifetime mostly out. Remaining suspect: L2 interaction with the
//      0xAA out-poison fill that runs right before us in the graph (same
//      128MiB of lines, freshly dirty, mid-writeback). R12: nontemporal
//      stores (nt flag) to bypass L2 allocate/LRU churn. Single change vs R11.
//      (R12 compile fix: __builtin_nontemporal_store needs a clang vector
//      type, not HIP_vector_type float4 -> use ext_vector_type(4) alias.)
#define FEATURES 512

typedef float v4f __attribute__((ext_vector_type(4)));

__device__ __forceinline__ float fast_sigm(float v) {
    const float L2E = 1.44269504f;
    float e = __builtin_amdgcn_exp2f(-L2E * v);
    return __builtin_amdgcn_rcpf(1.0f + e);
}
__device__ __forceinline__ float fast_tanh(float v) {
    const float L2E2 = 2.88539008f;
    float e = __builtin_amdgcn_exp2f(L2E2 * v);
    return 1.0f - 2.0f * __builtin_amdgcn_rcpf(e + 1.0f);
}

// 512 blocks x 256 threads = 2048 waves; each wave owns one contiguous 64KB
// segment (2048 x 64KB = 128MiB exactly). Thread 0 computes the recurrence
// (bitwise fixed-point early exit); remainder filled by all 256 threads.
__global__ __launch_bounds__(256) void bitpred_kernel(
    const float* __restrict__ Wi, const float* __restrict__ Wh,
    const float* __restrict__ b, float* __restrict__ out,
    long long total4)
{
    __shared__ float hrow[FEATURES];
    __shared__ float s_hf;
    __shared__ int s_t;

    if (threadIdx.x == 0) {
        // x == h invariant (x0 = h0 = 0, x_{t+1} = h_{t+1}) => gates use Wi+Wh.
        const float w0 = Wi[0] + Wh[0], w1 = Wi[1] + Wh[1];
        const float w2 = Wi[2] + Wh[2], w3 = Wi[3] + Wh[3];
        const float b0 = b[0], b1 = b[1], b2 = b[2], b3 = b[3];
        float c = 0.f, h = 0.f;
        float pc = 0.f, ph = 0.f;
        int t = 0;
        for (; t < FEATURES; ++t) {
            // gate order from jnp.split: i, f, g, o
            float gi = fmaf(h, w0, b0);
            float gf = fmaf(h, w1, b1);
            float gg = fmaf(h, w2, b2);
            float go = fmaf(h, w3, b3);
            c = fast_sigm(gf) * c + fast_sigm(gi) * fast_tanh(gg);
            h = fast_sigm(go) * fast_tanh(c);
            hrow[t] = h;
            // Bitwise fixed point => all subsequent h identical. (b=0: t=0.)
            if (c == pc && h == ph) break;
            pc = c; ph = h;
        }
        s_hf = h;
        s_t = t;
    }
    __syncthreads();
    // Parallel remainder fill.
    {
        const float hf = s_hf;
        for (int k = s_t + 1 + (int)threadIdx.x; k < FEATURES; k += 256)
            hrow[k] = hf;
    }
    __syncthreads();

    // Wave g owns float4s [g*4096, (g+1)*4096) = 64KB contiguous.
    // 4096 % 128 == 0: lane l only ever writes row float4s l and l+64,
    // alternating per 1KB burst. 64 bursts per wave, long-lived waves.
    const int lane = threadIdx.x & 63;
    const long long wave_g = (long long)blockIdx.x * 4 + (threadIdx.x >> 6);
    const long long base4 = wave_g * 4096;  // float4 units
    const v4f* hrow4 = (const v4f*)hrow;
    const v4f v0 = hrow4[lane];
    const v4f v1 = hrow4[lane + 64];
    v4f* __restrict__ out4 = (v4f*)out;
    if (base4 < total4) {
#pragma unroll 8
        for (int it = 0; it < 64; it += 2) {
            // nt stores: bypass L2 allocate/LRU; decouple from the poison
            // fill's dirty-line writeback over the same addresses.
            __builtin_nontemporal_store(v0, &out4[base4 + it * 64 + lane]);
            __builtin_nontemporal_store(v1, &out4[base4 + (it + 1) * 64 + lane]);
        }
    }
}

extern "C" void kernel_launch(void* const* d_in, const int* in_sizes, int n_in,
                              void* d_out, int out_size, void* d_ws, size_t ws_size,
                              hipStream_t stream) {
    // setup_inputs order: batch_size (int scalar), Wi (4 f32), Wh (4 f32), b (4 f32)
    const float* Wi = (const float*)d_in[1];
    const float* Wh = (const float*)d_in[2];
    const float* b  = (const float*)d_in[3];
    float* out = (float*)d_out;

    long long total4 = (long long)out_size / 4;  // 8,388,608 float4s (128 MiB)
    hipLaunchKernelGGL(bitpred_kernel, dim3(512), dim3(256), 0, stream,
                       Wi, Wh, b, out, total4);
}

// Round 17
// 138.128 us; speedup vs baseline: 1.0365x; 1.0365x over previous
//
#include <hip/hip_runtime.h>

// BitPredictor: scalar LSTM (hidden=1) iterated FEATURES times; output is one
// 512-float row broadcast across the 65536-row batch (batch dim degenerate).
//
// R2:  380us = single-lane serial recurrence -> fixed-point early exit +
//      exp2/rcp gates. Kernel ~40us after.
// R7/R9: opposite store layouts both ~3.2 TB/s vs fill 6.6 -> addressing out.
// R11: long-lived waves (2048 waves x 64 stores): 40->35us. Direction real.
// R13: nt stores: null (L2 path exonerated). Reverted to plain stores.
// R14: match the 6.5 TB/s fill's shape exactly: 256 blocks x 192 threads
//      = 3 waves/CU on ALL 256 CUs (fill occupancy 9.6%), grid-stride dense
//      window, ~171 bursts per thread (fill-like long-lived waves).
#define FEATURES 512

__device__ __forceinline__ float fast_sigm(float v) {
    const float L2E = 1.44269504f;
    float e = __builtin_amdgcn_exp2f(-L2E * v);
    return __builtin_amdgcn_rcpf(1.0f + e);
}
__device__ __forceinline__ float fast_tanh(float v) {
    const float L2E2 = 2.88539008f;
    float e = __builtin_amdgcn_exp2f(L2E2 * v);
    return 1.0f - 2.0f * __builtin_amdgcn_rcpf(e + 1.0f);
}

// 256 blocks x 192 threads: one block per CU, 3 waves each. Thread 0 computes
// the recurrence into LDS (bitwise fixed-point early exit); remainder filled
// in parallel; then a fill-shaped grid-stride store loop.
__global__ __launch_bounds__(192) void bitpred_kernel(
    const float* __restrict__ Wi, const float* __restrict__ Wh,
    const float* __restrict__ b, float* __restrict__ out,
    long long total4)
{
    __shared__ float hrow[FEATURES];
    __shared__ float s_hf;
    __shared__ int s_t;

    if (threadIdx.x == 0) {
        // x == h invariant (x0 = h0 = 0, x_{t+1} = h_{t+1}) => gates use Wi+Wh.
        const float w0 = Wi[0] + Wh[0], w1 = Wi[1] + Wh[1];
        const float w2 = Wi[2] + Wh[2], w3 = Wi[3] + Wh[3];
        const float b0 = b[0], b1 = b[1], b2 = b[2], b3 = b[3];
        float c = 0.f, h = 0.f;
        float pc = 0.f, ph = 0.f;
        int t = 0;
        for (; t < FEATURES; ++t) {
            // gate order from jnp.split: i, f, g, o
            float gi = fmaf(h, w0, b0);
            float gf = fmaf(h, w1, b1);
            float gg = fmaf(h, w2, b2);
            float go = fmaf(h, w3, b3);
            c = fast_sigm(gf) * c + fast_sigm(gi) * fast_tanh(gg);
            h = fast_sigm(go) * fast_tanh(c);
            hrow[t] = h;
            // Bitwise fixed point => all subsequent h identical. (b=0: t=0.)
            if (c == pc && h == ph) break;
            pc = c; ph = h;
        }
        s_hf = h;
        s_t = t;
    }
    __syncthreads();
    // Parallel remainder fill.
    {
        const float hf = s_hf;
        for (int k = s_t + 1 + (int)threadIdx.x; k < FEATURES; k += 192)
            hrow[k] = hf;
    }
    __syncthreads();

    // Fill-shaped store loop: 49152 threads, dense 768KB instantaneous
    // window advancing sequentially. 49152 % 128 == 0 => each thread's row
    // float4 index (gid & 127) is loop-invariant: load once, store ~171x.
    const long long nthreads = 49152;  // 256 * 192
    const long long gid = (long long)blockIdx.x * 192 + threadIdx.x;
    const float4* hrow4 = (const float4*)hrow;
    const float4 val = hrow4[gid & 127];
    float4* __restrict__ out4 = (float4*)out;
#pragma unroll 4
    for (long long i = gid; i < total4; i += nthreads) {
        out4[i] = val;
    }
}

extern "C" void kernel_launch(void* const* d_in, const int* in_sizes, int n_in,
                              void* d_out, int out_size, void* d_ws, size_t ws_size,
                              hipStream_t stream) {
    // setup_inputs order: batch_size (int scalar), Wi (4 f32), Wh (4 f32), b (4 f32)
    const float* Wi = (const float*)d_in[1];
    const float* Wh = (const float*)d_in[2];
    const float* b  = (const float*)d_in[3];
    float* out = (float*)d_out;

    long long total4 = (long long)out_size / 4;  // 8,388,608 float4s (128 MiB)
    hipLaunchKernelGGL(bitpred_kernel, dim3(256), dim3(192), 0, stream,
                       Wi, Wh, b, out, total4);
}